// Round 8
// baseline (1043.427 us; speedup 1.0000x reference)
//
#include <hip/hip_runtime.h>
#include <hip/hip_bf16.h>

// Problem constants (from reference)
#define L_SEQ   2048
#define DMODEL  1024
#define DINNER  2048
#define DSTATE  16
#define DTRANK  64
#define DCONV   4
#define NLAYER  4
#define XDIM    96   // DTRANK + 2*DSTATE
#define CHUNK   32
#define NCHUNK  (L_SEQ / CHUNK)   // 64
#define KSPLIT  8                 // x_proj split-K factor
#define LOG2E   1.4426950408889634f

typedef __attribute__((ext_vector_type(8))) short bf16x8;
typedef __attribute__((ext_vector_type(4))) float f32x4;

__device__ __forceinline__ float bf2f(unsigned short u) {
    union { unsigned int i; float f; } v; v.i = ((unsigned int)u) << 16; return v.f;
}
__device__ __forceinline__ unsigned short f2bf(float f) {
    union { float f; unsigned int i; } v; v.f = f;
    unsigned int x = v.i;
    unsigned int r = (x + 0x7fffu + ((x >> 16) & 1u)) >> 16;  // RTNE
    return (unsigned short)r;
}
__device__ __forceinline__ float ldin(const void* p, size_t idx, bool bf) {
    return bf ? bf2f(((const unsigned short*)p)[idx]) : ((const float*)p)[idx];
}

// ---------------------------------------------------------------------------
// Dtype detector: A_log[0] = log(1) = 0.  fp32 -> first u32 == 0x00000000.
// ---------------------------------------------------------------------------
__global__ void k_detect(const unsigned int* __restrict__ Alog_u32, int* __restrict__ flag) {
    *flag = (Alog_u32[0] != 0u) ? 1 : 0;
}

// ---------------------------------------------------------------------------
// Combined per-layer weight cast fp32 -> bf16 (no-op when inputs are bf16).
// ---------------------------------------------------------------------------
#define N_IP (2 * DINNER * DMODEL)   // 4,194,304
#define N_XP (XDIM * DINNER)         //   196,608
#define N_DT (DINNER * DTRANK)       //   131,072
#define N_OP (DMODEL * DINNER)       // 2,097,152
#define N_CAST_TOT (N_IP + N_XP + N_DT + N_OP)

__global__ __launch_bounds__(256) void k_castall(
    const void* __restrict__ ipw, const void* __restrict__ xpw,
    const void* __restrict__ dtw, const void* __restrict__ opw,
    size_t o_ip, size_t o_xp, size_t o_dt, size_t o_op,
    unsigned short* __restrict__ w_ip, unsigned short* __restrict__ w_xp,
    unsigned short* __restrict__ w_dt, unsigned short* __restrict__ w_op,
    const int* __restrict__ flagp)
{
    if (*flagp) return;
    int i = (blockIdx.x * 256 + threadIdx.x) * 4;
    const float* src; unsigned short* dst;
    if (i < N_IP)                       { src = (const float*)ipw + o_ip + i; dst = w_ip + i; }
    else if ((i -= N_IP) < N_XP)        { src = (const float*)xpw + o_xp + i; dst = w_xp + i; }
    else if ((i -= N_XP) < N_DT)        { src = (const float*)dtw + o_dt + i; dst = w_dt + i; }
    else if ((i -= N_DT) < N_OP)        { src = (const float*)opw + o_op + i; dst = w_op + i; }
    else return;
    const float4 v = *(const float4*)src;
    ushort4 o;
    o.x = f2bf(v.x); o.y = f2bf(v.y); o.z = f2bf(v.z); o.w = f2bf(v.w);
    *(ushort4*)dst = o;
}

// ---------------------------------------------------------------------------
// Fused (out_proj partial-sum) + residual add + RMSNorm -> bf16 normed out.
// first=1: residual = hidden_states input. else: residual += p0 + p1.
// ---------------------------------------------------------------------------
__global__ __launch_bounds__(256) void k_addnorm(
    const float* __restrict__ parts, const void* __restrict__ hs,
    float* __restrict__ resid, unsigned short* __restrict__ hnorm,
    const void* __restrict__ w, size_t woff, int first,
    const int* __restrict__ flagp)
{
    const bool bf = (*flagp != 0);
    const int row = blockIdx.x;
    const int col = threadIdx.x * 4;
    const size_t base = (size_t)row * DMODEL + col;
    float r[4];
    if (first) {
        if (bf) {
            const ushort4 v = *(const ushort4*)((const unsigned short*)hs + base);
            r[0] = bf2f(v.x); r[1] = bf2f(v.y); r[2] = bf2f(v.z); r[3] = bf2f(v.w);
        } else {
            const float4 v = *(const float4*)((const float*)hs + base);
            r[0] = v.x; r[1] = v.y; r[2] = v.z; r[3] = v.w;
        }
    } else {
        const float4 p0 = *(const float4*)(parts + base);
        const float4 p1 = *(const float4*)(parts + (size_t)L_SEQ * DMODEL + base);
        const float4 rv = *(const float4*)(resid + base);
        r[0] = p0.x + p1.x + rv.x; r[1] = p0.y + p1.y + rv.y;
        r[2] = p0.z + p1.z + rv.z; r[3] = p0.w + p1.w + rv.w;
    }
    *(float4*)(resid + base) = make_float4(r[0], r[1], r[2], r[3]);
    float ss = r[0]*r[0] + r[1]*r[1] + r[2]*r[2] + r[3]*r[3];
    #pragma unroll
    for (int o = 32; o > 0; o >>= 1) ss += __shfl_down(ss, o);
    __shared__ float red[4];
    const int lane = threadIdx.x & 63, wv = threadIdx.x >> 6;
    if (lane == 0) red[wv] = ss;
    __syncthreads();
    const float total = red[0] + red[1] + red[2] + red[3];
    const float scale = rsqrtf(total * (1.0f / DMODEL) + 1e-5f);
    const float w0 = ldin(w, woff + col + 0, bf), w1 = ldin(w, woff + col + 1, bf);
    const float w2 = ldin(w, woff + col + 2, bf), w3 = ldin(w, woff + col + 3, bf);
    ushort4 o;
    o.x = f2bf(r[0] * scale * w0); o.y = f2bf(r[1] * scale * w1);
    o.z = f2bf(r[2] * scale * w2); o.w = f2bf(r[3] * scale * w3);
    *(ushort4*)(hnorm + base) = o;
}

// ---------------------------------------------------------------------------
// MFMA NT GEMM: C[M,N] = A[M,K]_bf16 * W[N,K]^T_bf16.
// 128x64 tile, 256 thr (2m x 2n waves; wave = 64x32), BK=32.
// LDS in FRAGMENT-LINEAR layout: 16B unit (r,c) at index (r>>4)*64+c*16+(r&15)
//  -> staged unit index == tid (writes lane-linear, zero conflicts)
//  -> MFMA fragment reads are base + lane*16B (zero conflicts by construction)
// Register prefetch of next K-tile. blockIdx.x = n-tile (XCD/L2 locality),
// blockIdx.y = m-tile, blockIdx.z = split-K slice.
// mode: 0 fp32 C, 1 softplus+bias fp32 C, 2 bf16 C.
// ---------------------------------------------------------------------------
__global__ __launch_bounds__(256) void k_gemm_mfma(
    const unsigned short* __restrict__ A, int lda,
    const void* __restrict__ Worig, size_t woff,
    const unsigned short* __restrict__ Wconv, int ldw,
    void* __restrict__ C, int ldc, size_t czstride,
    int N, int Kslice,
    const void* __restrict__ bias, size_t boff, int mode,
    const int* __restrict__ flagp)
{
    const bool bf = (*flagp != 0);
    __shared__ unsigned short lA[4096];   // 128 x 32 (8 KB)
    __shared__ unsigned short lB[2048];   // 64 x 32  (4 KB)
    const int tid = threadIdx.x;
    const int n0 = blockIdx.x * 64;
    const int m0 = blockIdx.y * 128;
    const int k0 = blockIdx.z * Kslice;

    const int w    = tid >> 6;
    const int lane = tid & 63;
    const int wm = (w >> 1) * 64, wn = (w & 1) * 32;
    const int m16 = lane & 15;

    // staging: thread t -> A units t, t+256; B unit t.  unit t = (row,chunk):
    const int sr = ((tid >> 6) << 4) | (tid & 15);   // row 0..63
    const int sk = ((tid >> 4) & 3) * 8;             // k element offset

    const unsigned short* Wbase = bf ? ((const unsigned short*)Worig + woff) : Wconv;
    const int nrow = n0 + sr;
    const bool nok = (nrow < N);
    const unsigned short* ArowLo = A + (size_t)(m0 + sr) * lda + sk;
    const unsigned short* ArowHi = A + (size_t)(m0 + sr + 64) * lda + sk;
    const unsigned short* Wrow   = Wbase + (size_t)nrow * ldw + sk;

    f32x4 acc[4][2];
    #pragma unroll
    for (int i = 0; i < 4; ++i)
        #pragma unroll
        for (int j = 0; j < 2; ++j)
            acc[i][j] = (f32x4){0.f, 0.f, 0.f, 0.f};

    uint4 ra0, ra1, rb;
    ra0 = *(const uint4*)(ArowLo + k0);
    ra1 = *(const uint4*)(ArowHi + k0);
    rb = (uint4){0u, 0u, 0u, 0u};
    if (nok) rb = *(const uint4*)(Wrow + k0);

    for (int kb = 0; kb < Kslice; kb += 32) {
        *(uint4*)&lA[tid * 8]        = ra0;
        *(uint4*)&lA[tid * 8 + 2048] = ra1;
        *(uint4*)&lB[tid * 8]        = rb;
        __syncthreads();
        if (kb + 32 < Kslice) {   // prefetch next tile (completes during MFMA)
            const int kk = k0 + kb + 32;
            ra0 = *(const uint4*)(ArowLo + kk);
            ra1 = *(const uint4*)(ArowHi + kk);
            if (nok) rb = *(const uint4*)(Wrow + kk);
        }
        bf16x8 af[4], bfr[2];
        #pragma unroll
        for (int i = 0; i < 4; ++i)
            af[i] = *(const bf16x8*)&lA[(((w >> 1) * 4 + i) * 64 + lane) * 8];
        #pragma unroll
        for (int j = 0; j < 2; ++j)
            bfr[j] = *(const bf16x8*)&lB[(((w & 1) * 2 + j) * 64 + lane) * 8];
        #pragma unroll
        for (int i = 0; i < 4; ++i)
            #pragma unroll
            for (int j = 0; j < 2; ++j)
                acc[i][j] = __builtin_amdgcn_mfma_f32_16x16x32_bf16(af[i], bfr[j], acc[i][j], 0, 0, 0);
        __syncthreads();
    }
    // epilogue: D row=(lane>>4)*4+reg, col=lane&15  [verified gfx950 layout]
    const int rowb = (lane >> 4) * 4;
    float* Cf = (float*)C + (size_t)blockIdx.z * czstride;
    unsigned short* Ch = (unsigned short*)C;
    #pragma unroll
    for (int j = 0; j < 2; ++j) {
        const int col = n0 + wn + j * 16 + m16;
        if (col < N) {
            float bv = 0.f;
            if (mode == 1) bv = ldin(bias, boff + col, bf);
            #pragma unroll
            for (int i = 0; i < 4; ++i) {
                #pragma unroll
                for (int r = 0; r < 4; ++r) {
                    const int row = m0 + wm + i * 16 + rowb + r;
                    float v = acc[i][j][r];
                    if (mode == 1) { v += bv; v = (v > 20.f) ? v : log1pf(__expf(v)); }
                    if (mode == 2) Ch[(size_t)row * ldc + col] = f2bf(v);
                    else           Cf[(size_t)row * ldc + col] = v;
                }
            }
        }
    }
}

// ---------------------------------------------------------------------------
// Causal depthwise conv (k=4) + bias + SiLU.  xz bf16 -> uc bf16.
// ---------------------------------------------------------------------------
__global__ __launch_bounds__(256) void k_conv(
    const unsigned short* __restrict__ xz, const void* __restrict__ cw, size_t cwoff,
    const void* __restrict__ cb, size_t cboff,
    unsigned short* __restrict__ uc,
    const int* __restrict__ flagp)
{
    const bool bf = (*flagp != 0);
    const int idx = blockIdx.x * 256 + threadIdx.x;
    const int d = idx & (DINNER - 1);
    const int l = idx >> 11;
    const float w0 = ldin(cw, cwoff + d * 4 + 0, bf), w1 = ldin(cw, cwoff + d * 4 + 1, bf);
    const float w2 = ldin(cw, cwoff + d * 4 + 2, bf), w3 = ldin(cw, cwoff + d * 4 + 3, bf);
    float acc = ldin(cb, cboff + d, bf);
    if (l >= 3) acc = fmaf(bf2f(xz[(size_t)(l - 3) * (2 * DINNER) + d]), w0, acc);
    if (l >= 2) acc = fmaf(bf2f(xz[(size_t)(l - 2) * (2 * DINNER) + d]), w1, acc);
    if (l >= 1) acc = fmaf(bf2f(xz[(size_t)(l - 1) * (2 * DINNER) + d]), w2, acc);
    acc = fmaf(bf2f(xz[(size_t)l * (2 * DINNER) + d]), w3, acc);
    const float sig = 1.f / (1.f + __expf(-acc));
    uc[(size_t)l * DINNER + d] = f2bf(acc * sig);
}

// ---------------------------------------------------------------------------
// x_proj split-K reduce: xdbl = sum of KSPLIT partials; dual write fp32+bf16.
// ---------------------------------------------------------------------------
__global__ __launch_bounds__(256) void k_reduce(
    const float* __restrict__ parts, float* __restrict__ xdbl,
    unsigned short* __restrict__ xdbl_bf)
{
    const int idx = blockIdx.x * 256 + threadIdx.x;
    float s = 0.f;
    #pragma unroll
    for (int z = 0; z < KSPLIT; ++z)
        s += parts[(size_t)z * L_SEQ * XDIM + idx];
    xdbl[idx] = s;
    xdbl_bf[idx] = f2bf(s);
}

// ---------------------------------------------------------------------------
// Chunked selective scan, pass 1: local scan from h=0 per (channels, chunk).
// exp2-folded A; next-step prefetch.
// ---------------------------------------------------------------------------
__global__ __launch_bounds__(128) void k_scan1(
    const float* __restrict__ delta, const unsigned short* __restrict__ uc,
    const float* __restrict__ xdbl,
    const void* __restrict__ Alog, size_t aoff,
    float* __restrict__ hloc, float* __restrict__ sdelta,
    const int* __restrict__ flagp)
{
    const bool bf = (*flagp != 0);
    __shared__ float sB[CHUNK][DSTATE];
    const int d = blockIdx.x * 128 + threadIdx.x;
    const int c = blockIdx.y;
    const int t0 = c * CHUNK;
    float A2[DSTATE];
    #pragma unroll
    for (int n = 0; n < DSTATE; ++n)
        A2[n] = -__expf(ldin(Alog, aoff + (size_t)d * DSTATE + n, bf)) * LOG2E;
    #pragma unroll
    for (int r = 0; r < 4; ++r) {
        const int idx = r * 128 + threadIdx.x;
        const int tt = idx >> 4, n = idx & 15;
        sB[tt][n] = xdbl[(size_t)(t0 + tt) * XDIM + DTRANK + n];
    }
    __syncthreads();
    float h[DSTATE];
    #pragma unroll
    for (int n = 0; n < DSTATE; ++n) h[n] = 0.f;
    float sd = 0.f;
    float dcur = delta[(size_t)t0 * DINNER + d];
    float ucur = bf2f(uc[(size_t)t0 * DINNER + d]);
    for (int ti = 0; ti < CHUNK; ++ti) {
        float dnx = 0.f, unx = 0.f;
        if (ti < CHUNK - 1) {
            const size_t nxt = (size_t)(t0 + ti + 1) * DINNER + d;
            dnx = delta[nxt];
            unx = bf2f(uc[nxt]);
        }
        sd += dcur;
        const float du = dcur * ucur;
        #pragma unroll
        for (int n = 0; n < DSTATE; ++n) {
            const float dA = exp2f(dcur * A2[n]);
            h[n] = fmaf(dA, h[n], du * sB[ti][n]);
        }
        dcur = dnx; ucur = unx;
    }
    float* hp = hloc + ((size_t)c * DINNER + d) * DSTATE;
    #pragma unroll
    for (int n = 0; n < DSTATE; n += 4)
        *(float4*)(hp + n) = make_float4(h[n], h[n + 1], h[n + 2], h[n + 3]);
    sdelta[(size_t)c * DINNER + d] = sd;
}

// ---------------------------------------------------------------------------
// Pass 2: per (d,n) sequential scan over chunk states; in-place -> Hin[c].
// ---------------------------------------------------------------------------
__global__ __launch_bounds__(256) void k_scan2(
    float* __restrict__ hloc, const float* __restrict__ sdelta,
    const void* __restrict__ Alog, size_t aoff,
    const int* __restrict__ flagp)
{
    const bool bf = (*flagp != 0);
    const int gid = blockIdx.x * 256 + threadIdx.x;
    const int d = gid >> 4, n = gid & 15;
    const float A2 = -__expf(ldin(Alog, aoff + (size_t)d * DSTATE + n, bf)) * LOG2E;
    float carry = 0.f;
    for (int c = 0; c < NCHUNK; ++c) {
        const size_t idx = ((size_t)c * DINNER + d) * DSTATE + n;
        const float tmp = hloc[idx];
        hloc[idx] = carry;
        const float P = exp2f(A2 * sdelta[(size_t)c * DINNER + d]);
        carry = fmaf(P, carry, tmp);
    }
}

// ---------------------------------------------------------------------------
// Pass 3: local scan seeded with Hin[c]; y=(C.h+uc*D)*silu(z) as bf16.
// ---------------------------------------------------------------------------
__global__ __launch_bounds__(128) void k_scan3(
    const float* __restrict__ delta, const unsigned short* __restrict__ uc,
    const unsigned short* __restrict__ xz, const float* __restrict__ xdbl,
    const void* __restrict__ Alog, size_t aoff,
    const void* __restrict__ Dp, size_t doff,
    const float* __restrict__ hin, unsigned short* __restrict__ y,
    const int* __restrict__ flagp)
{
    const bool bf = (*flagp != 0);
    __shared__ float sBC[CHUNK][2 * DSTATE];
    const int d = blockIdx.x * 128 + threadIdx.x;
    const int c = blockIdx.y;
    const int t0 = c * CHUNK;
    float A2[DSTATE];
    #pragma unroll
    for (int n = 0; n < DSTATE; ++n)
        A2[n] = -__expf(ldin(Alog, aoff + (size_t)d * DSTATE + n, bf)) * LOG2E;
    const float Dv = ldin(Dp, doff + d, bf);
    #pragma unroll
    for (int r = 0; r < 8; ++r) {
        const int idx = r * 128 + threadIdx.x;
        const int tt = idx >> 5, n = idx & 31;
        sBC[tt][n] = xdbl[(size_t)(t0 + tt) * XDIM + DTRANK + n];
    }
    __syncthreads();
    float h[DSTATE];
    const float* hp = hin + ((size_t)c * DINNER + d) * DSTATE;
    #pragma unroll
    for (int n = 0; n < DSTATE; n += 4) {
        const float4 v = *(const float4*)(hp + n);
        h[n] = v.x; h[n + 1] = v.y; h[n + 2] = v.z; h[n + 3] = v.w;
    }
    float dcur = delta[(size_t)t0 * DINNER + d];
    float ucur = bf2f(uc[(size_t)t0 * DINNER + d]);
    float zcur = bf2f(xz[(size_t)t0 * (2 * DINNER) + DINNER + d]);
    for (int ti = 0; ti < CHUNK; ++ti) {
        float dnx = 0.f, unx = 0.f, znx = 0.f;
        if (ti < CHUNK - 1) {
            const size_t nxt = (size_t)(t0 + ti + 1) * DINNER + d;
            dnx = delta[nxt];
            unx = bf2f(uc[nxt]);
            znx = bf2f(xz[(size_t)(t0 + ti + 1) * (2 * DINNER) + DINNER + d]);
        }
        const float du = dcur * ucur;
        float dot = 0.f;
        #pragma unroll
        for (int n = 0; n < DSTATE; ++n) {
            const float dA = exp2f(dcur * A2[n]);
            h[n] = fmaf(dA, h[n], du * sBC[ti][n]);
            dot = fmaf(h[n], sBC[ti][DSTATE + n], dot);
        }
        const float sig = 1.f / (1.f + __expf(-zcur));
        y[(size_t)(t0 + ti) * DINNER + d] = f2bf((dot + ucur * Dv) * (zcur * sig));
        dcur = dnx; ucur = unx; zcur = znx;
    }
}

// ---------------------------------------------------------------------------
// Final: out = (p0 + p1) + residual, dtype per flag
// ---------------------------------------------------------------------------
__global__ __launch_bounds__(256) void k_final(
    const float* __restrict__ parts, const float* __restrict__ resid,
    void* __restrict__ out, const int* __restrict__ flagp)
{
    const bool bf = (*flagp != 0);
    const int i = (blockIdx.x * 256 + threadIdx.x) * 4;
    const float4 a = *(const float4*)(parts + i);
    const float4 c = *(const float4*)(parts + (size_t)L_SEQ * DMODEL + i);
    const float4 b = *(const float4*)(resid + i);
    const float o0 = a.x + c.x + b.x, o1 = a.y + c.y + b.y;
    const float o2 = a.z + c.z + b.z, o3 = a.w + c.w + b.w;
    if (bf) {
        ushort4 o;
        o.x = f2bf(o0); o.y = f2bf(o1); o.z = f2bf(o2); o.w = f2bf(o3);
        *(ushort4*)((unsigned short*)out + i) = o;
    } else {
        *(float4*)((float*)out + i) = make_float4(o0, o1, o2, o3);
    }
}

extern "C" void kernel_launch(void* const* d_in, const int* in_sizes, int n_in,
                              void* d_out, int out_size, void* d_ws, size_t ws_size,
                              hipStream_t stream)
{
    const void* hs    = d_in[0];
    const void* normw = d_in[1];
    const void* ipw   = d_in[2];
    const void* cw    = d_in[3];
    const void* cb    = d_in[4];
    const void* xpw   = d_in[5];
    const void* dtw   = d_in[6];
    const void* dtb   = d_in[7];
    const void* Alog  = d_in[8];
    const void* Dp    = d_in[9];
    const void* opw   = d_in[10];

    // fp32 region
    float* ws     = (float*)d_ws;
    float* resid  = ws;                                        // 2,097,152
    float* xdblb  = resid  + (size_t)L_SEQ * DMODEL;           //   196,608
    float* deltab = xdblb  + (size_t)L_SEQ * XDIM;             // 4,194,304 (parts overlays)
    float* hlocb  = deltab + (size_t)L_SEQ * DINNER;           // 2,097,152
    float* sdeltab= hlocb  + (size_t)NCHUNK * DINNER * DSTATE; //   131,072
    // bf16 region
    unsigned short* hn_bf   = (unsigned short*)(sdeltab + (size_t)NCHUNK * DINNER);
    unsigned short* xz_bf   = hn_bf   + (size_t)L_SEQ * DMODEL;
    unsigned short* uc_bf   = xz_bf   + (size_t)L_SEQ * 2 * DINNER;
    unsigned short* xdbl_bf = uc_bf   + (size_t)L_SEQ * DINNER;
    unsigned short* y_bf    = xdbl_bf + (size_t)L_SEQ * XDIM;
    unsigned short* w_ip    = y_bf   + (size_t)L_SEQ * DINNER;
    unsigned short* w_xp    = w_ip   + (size_t)2 * DINNER * DMODEL;
    unsigned short* w_dt    = w_xp   + (size_t)XDIM * DINNER;
    unsigned short* w_op    = w_dt   + (size_t)DINNER * DTRANK;
    int*            flagp   = (int*)(w_op + (size_t)DMODEL * DINNER);

    // overlays on deltab (stream-ordered, hazard-checked):
    //  - addnorm(layer i) reads prev layer's partsO, THEN x_proj writes partsX,
    //    THEN dt_proj writes deltab, scan consumes, out_proj writes partsO.
    float* partsX  = deltab;   // KSPLIT*L*XDIM = 1,572,864 <= 4,194,304
    float* partsO  = deltab;   // 2*L*DMODEL    = 4,194,304 == capacity

    k_detect<<<1, 1, 0, stream>>>((const unsigned int*)Alog, flagp);

    for (int i = 0; i < NLAYER; ++i) {
        const size_t o_ipw = (size_t)i * 2 * DINNER * DMODEL;
        const size_t o_xpw = (size_t)i * XDIM * DINNER;
        const size_t o_dtw = (size_t)i * DINNER * DTRANK;
        const size_t o_opw = (size_t)i * DMODEL * DINNER;
        const size_t o_al  = (size_t)i * DINNER * DSTATE;

        k_castall<<<(N_CAST_TOT / 4 + 255) / 256, 256, 0, stream>>>(
            ipw, xpw, dtw, opw, o_ipw, o_xpw, o_dtw, o_opw,
            w_ip, w_xp, w_dt, w_op, flagp);

        k_addnorm<<<L_SEQ, 256, 0, stream>>>(
            partsO, hs, resid, hn_bf, normw, (size_t)i * DMODEL, i == 0 ? 1 : 0, flagp);
        // in_proj: (2048 x 1024) @ (4096 x 1024)^T -> xz bf16  [1024 blocks]
        k_gemm_mfma<<<dim3(64, 16, 1), 256, 0, stream>>>(
            hn_bf, DMODEL, ipw, o_ipw, w_ip, DMODEL,
            xz_bf, 2 * DINNER, 0, 2 * DINNER, DMODEL, nullptr, 0, 2, flagp);
        k_conv<<<(L_SEQ * DINNER) / 256, 256, 0, stream>>>(
            xz_bf, cw, (size_t)i * DINNER * DCONV, cb, (size_t)i * DINNER, uc_bf, flagp);
        // x_proj split-K=8: (2048 x 2048) @ (96 x 2048)^T -> partials [256 blocks]
        k_gemm_mfma<<<dim3(2, 16, KSPLIT), 256, 0, stream>>>(
            uc_bf, DINNER, xpw, o_xpw, w_xp, DINNER,
            partsX, XDIM, (size_t)L_SEQ * XDIM, XDIM, DINNER / KSPLIT,
            nullptr, 0, 0, flagp);
        k_reduce<<<(L_SEQ * XDIM) / 256, 256, 0, stream>>>(partsX, xdblb, xdbl_bf);
        // dt_proj + softplus: (2048 x 64) @ (2048 x 64)^T -> delta  [512 blocks]
        k_gemm_mfma<<<dim3(32, 16, 1), 256, 0, stream>>>(
            xdbl_bf, XDIM, dtw, o_dtw, w_dt, DTRANK,
            deltab, DINNER, 0, DINNER, DTRANK, dtb, (size_t)i * DINNER, 1, flagp);
        // chunk-parallel selective scan (CHUNK=32 -> 1024 blocks/pass)
        k_scan1<<<dim3(DINNER / 128, NCHUNK), 128, 0, stream>>>(
            deltab, uc_bf, xdblb, Alog, o_al, hlocb, sdeltab, flagp);
        k_scan2<<<(DINNER * DSTATE) / 256, 256, 0, stream>>>(
            hlocb, sdeltab, Alog, o_al, flagp);
        k_scan3<<<dim3(DINNER / 128, NCHUNK), 128, 0, stream>>>(
            deltab, uc_bf, xz_bf, xdblb, Alog, o_al, Dp, (size_t)i * DINNER,
            hlocb, y_bf, flagp);
        // out_proj split-K=2: (2048 x 2048) @ (1024 x 2048)^T -> partials [512 blocks]
        k_gemm_mfma<<<dim3(16, 16, 2), 256, 0, stream>>>(
            y_bf, DINNER, opw, o_opw, w_op, DINNER,
            partsO, DMODEL, (size_t)L_SEQ * DMODEL, DMODEL, DINNER / 2,
            nullptr, 0, 0, flagp);
    }
    k_final<<<(L_SEQ * DMODEL) / 1024, 256, 0, stream>>>(partsO, resid, d_out, flagp);
}